// Round 3
// baseline (85.456 us; speedup 1.0000x reference)
//
#include <hip/hip_runtime.h>
#include <math.h>

#define NN 2000
#define WS_E 0        // expE[16][2000] normalized: exp(E)/rowsum
#define WS_P 32000    // P[1024][16] hidden-state prob rows (t used: 0..999)

// ---------------------------------------------------------------------------
// Prep. Blocks 1..16: expE row s = exp(E[s,:]) / sum. Block 0: all P rows via
// log-depth doubling (no long serial chains, ~25 barriers, all parallel).
// ---------------------------------------------------------------------------
__global__ __launch_bounds__(256) void prep_kernel(
    const float* __restrict__ init,   // (16,)
    const float* __restrict__ trans,  // (16,16)
    const float* __restrict__ emis,   // (16,2000)
    float* __restrict__ ws)
{
  __shared__ float red[256];
  __shared__ float Tpw[5][16][16];  // T^1, T^2, T^4, T^8, T^16
  __shared__ float M[16][16];       // scratch / T^(32k)
  __shared__ float C[32][16];       // checkpoints C[q] = p0 @ T^(32q)
  __shared__ float p0v[16];

  const int tid = threadIdx.x;
  const int b = blockIdx.x;

  if (b > 0) {
    // ---- emission row -> normalized prob domain (exp computed once ever) ----
    const int s = b - 1;
    const float4* rin = (const float4*)(emis + s * NN);   // 500 groups
    float4* rout = (float4*)(ws + WS_E + s * NN);
    const bool has2 = (tid + 256) < 500;
    float4 v0 = rin[tid];
    float4 v1 = has2 ? rin[tid + 256] : make_float4(0.f, 0.f, 0.f, 0.f);
    float4 e0, e1;
    e0.x = __expf(v0.x); e0.y = __expf(v0.y); e0.z = __expf(v0.z); e0.w = __expf(v0.w);
    float sm = e0.x + e0.y + e0.z + e0.w;
    if (has2) {
      e1.x = __expf(v1.x); e1.y = __expf(v1.y); e1.z = __expf(v1.z); e1.w = __expf(v1.w);
      sm += e1.x + e1.y + e1.z + e1.w;
    }
    red[tid] = sm; __syncthreads();
    for (int off = 128; off > 0; off >>= 1) {
      if (tid < off) red[tid] += red[tid + off];
      __syncthreads();
    }
    const float inv = 1.f / red[0];
    e0.x *= inv; e0.y *= inv; e0.z *= inv; e0.w *= inv;
    rout[tid] = e0;
    if (has2) {
      e1.x *= inv; e1.y *= inv; e1.z *= inv; e1.w *= inv;
      rout[tid + 256] = e1;
    }
    return;
  }

  // ---- block 0: P rows ----
  const int i = tid >> 4, j = tid & 15;

  M[i][j] = trans[tid];                 // raw trans staged
  if (tid < 16) {
    float m2 = -1e30f, s2 = 0.f;
    #pragma unroll
    for (int k = 0; k < 16; ++k) m2 = fmaxf(m2, init[k]);
    #pragma unroll
    for (int k = 0; k < 16; ++k) s2 += __expf(init[k] - m2);
    p0v[tid] = __expf(init[tid] - m2) / s2;
  }
  __syncthreads();

  // row softmax of T (redundant per-thread 16-elem row reduce)
  {
    float m = -1e30f;
    #pragma unroll
    for (int k = 0; k < 16; ++k) m = fmaxf(m, M[i][k]);
    float sm = 0.f;
    #pragma unroll
    for (int k = 0; k < 16; ++k) sm += __expf(M[i][k] - m);
    const float tp = __expf(M[i][j] - m) / sm;
    __syncthreads();
    Tpw[0][i][j] = tp;
  }
  __syncthreads();

  // squarings: Tpw[e+1] = Tpw[e]^2  (T^2,4,8,16), then M = T^32
  #pragma unroll
  for (int e = 0; e < 4; ++e) {
    float acc = 0.f;
    #pragma unroll
    for (int k = 0; k < 16; ++k) acc += Tpw[e][i][k] * Tpw[e][k][j];
    Tpw[e + 1][i][j] = acc;
    __syncthreads();
  }
  {
    float acc = 0.f;
    #pragma unroll
    for (int k = 0; k < 16; ++k) acc += Tpw[4][i][k] * Tpw[4][k][j];
    M[i][j] = acc;                      // M = T^32
  }
  if (tid < 16) C[0][tid] = p0v[tid];
  __syncthreads();

  // checkpoint doubling: C[k..2k-1] = C[0..k-1] @ M; M <- M^2
  #pragma unroll
  for (int s = 0; s < 5; ++s) {
    const int k = 1 << s;
    const bool active = (tid < k * 16);
    float accC = 0.f, accM = 0.f;
    if (active) {
      #pragma unroll
      for (int kk = 0; kk < 16; ++kk) accC += C[i][kk] * M[kk][j];
    }
    if (s < 4) {
      #pragma unroll
      for (int kk = 0; kk < 16; ++kk) accM += M[i][kk] * M[kk][j];
    }
    __syncthreads();
    if (active) C[k + i][j] = accC;
    if (s < 4) M[i][j] = accM;
    __syncthreads();
  }

  // row expansion into global: P[32q] = C[q]; then for d=1,2,4,8,16:
  // P[32q + r + d] = P[32q + r] @ T^d for r in [0, d)
  float* Pg = ws + WS_P;
  for (int x = tid; x < 32 * 16; x += 256)
    Pg[(x >> 4) * 32 * 16 + (x & 15)] = C[x >> 4][x & 15];
  __syncthreads();

  #pragma unroll
  for (int e = 0; e < 5; ++e) {
    const int d = 1 << e;
    const int total = 32 * d * 16;
    for (int x = tid; x < total; x += 256) {
      const int rr = x >> 4, jj = x & 15;
      const int q = rr >> e;            // rr / d
      const int r = d + (rr & (d - 1));
      const float* src = Pg + (32 * q + r - d) * 16;
      float acc = 0.f;
      #pragma unroll
      for (int kk = 0; kk < 16; ++kk) acc += src[kk] * Tpw[e][kk][jj];
      Pg[(32 * q + r) * 16 + jj] = acc;
    }
    __syncthreads();
  }
}

// ---------------------------------------------------------------------------
// Output: out[t,n] = log( sum_s P[t,s] * expE[s,n] ). Grid (2,250): block =
// 1024 n x 4 t; per thread 16 float4 loads (L2-hot), 256 FMA, 4 logs. No exp.
// ---------------------------------------------------------------------------
__global__ __launch_bounds__(256) void out_kernel(
    const float* __restrict__ ws, float* __restrict__ out)
{
  const int tid = threadIdx.x;
  const int n0 = blockIdx.x * 1024 + tid * 4;
  if (n0 + 3 >= NN) return;           // bx=1: threads >= 244 idle
  const int tbase = blockIdx.y * 4;

  float4 e[16];
  #pragma unroll
  for (int s = 0; s < 16; ++s)
    e[s] = *(const float4*)(ws + WS_E + s * NN + n0);

  #pragma unroll
  for (int tt = 0; tt < 4; ++tt) {
    const float* Pr = ws + WS_P + (tbase + tt) * 16;  // wave-uniform
    float4 acc = make_float4(0.f, 0.f, 0.f, 0.f);
    #pragma unroll
    for (int s = 0; s < 16; ++s) {
      const float p = Pr[s];
      acc.x += p * e[s].x; acc.y += p * e[s].y;
      acc.z += p * e[s].z; acc.w += p * e[s].w;
    }
    float4 o;
    o.x = __logf(acc.x); o.y = __logf(acc.y);
    o.z = __logf(acc.z); o.w = __logf(acc.w);
    *(float4*)(out + (tbase + tt) * NN + n0) = o;
  }
}

extern "C" void kernel_launch(void* const* d_in, const int* in_sizes, int n_in,
                              void* d_out, int out_size, void* d_ws, size_t ws_size,
                              hipStream_t stream) {
  const float* init  = (const float*)d_in[0];   // (16,)
  // d_in[1] chain weights: log_softmax rows -> logsumexp over chains == 0, cancels
  const float* emis  = (const float*)d_in[2];   // (16,2000)
  const float* trans = (const float*)d_in[3];   // (16,16)
  float* ws  = (float*)d_ws;                    // 192 KB used
  float* out = (float*)d_out;                   // (1000,2000) f32

  hipLaunchKernelGGL(prep_kernel, dim3(17), dim3(256), 0, stream,
                     init, trans, emis, ws);
  hipLaunchKernelGGL(out_kernel, dim3(2, 250), dim3(256), 0, stream, ws, out);
}

// Round 4
// 72.534 us; speedup vs baseline: 1.1782x; 1.1782x over previous
//
#include <hip/hip_runtime.h>
#include <math.h>

#define NN 2000

// Single fused kernel. Grid (2,250): blockIdx.y -> 4 consecutive t rows,
// blockIdx.x -> 1024-col n-half. Each block is fully independent:
//   A) emission row-sums Z_s (one exp pass, wave-per-4-states, shuffle reduce)
//   B) T^(4*by) by binary powering of T^4 (ping-pong LDS, 1 barrier/step)
//      then w rows, wd[t][s] = w[t][s]/Z_s
//   C) out[t,n] = log( sum_s wd[t][s] * exp(E[s,n]) ) for its n-half
// ~17 barriers total, 2 blocks/CU (8 waves/CU).
__global__ __launch_bounds__(256) void ssm_fused(
    const float* __restrict__ init,   // (16,)
    const float* __restrict__ emis,   // (16,2000)
    const float* __restrict__ trans,  // (16,16)
    float* __restrict__ out)          // (1000,2000)
{
  __shared__ float Tp[16][16];      // T^1 (prob domain)
  __shared__ float Bb[2][16][16];   // ping-pong: running squares
  __shared__ float Rb[2][16][16];   // ping-pong: result power
  __shared__ float Z[16];           // emission row sums
  __shared__ float wrow[4][16];     // w rows -> wd in place
  __shared__ float p0v[16];

  const int tid  = threadIdx.x;
  const int i    = tid >> 4, j = tid & 15;
  const int lane = tid & 63, wv = tid >> 6;

  // stage raw transition matrix (Rb[0] as temp)
  Rb[0][i][j] = trans[tid];

  // p0 = softmax(init), redundant in threads 0..15
  if (tid < 16) {
    float m = -1e30f, s2 = 0.f;
    #pragma unroll
    for (int k = 0; k < 16; ++k) m = fmaxf(m, init[k]);
    #pragma unroll
    for (int k = 0; k < 16; ++k) s2 += __expf(init[k] - m);
    p0v[tid] = __expf(init[tid] - m) / s2;
  }

  // ---- A: emission row sums; wave wv owns states 4wv..4wv+3 ----
  // (inputs ~N(0,1): expf safe without max-subtraction; validated absmax 0.031)
  float ssum[4] = {0.f, 0.f, 0.f, 0.f};
  for (int g = lane; g < 500; g += 64) {
    #pragma unroll
    for (int si = 0; si < 4; ++si) {
      const int s = wv * 4 + si;
      float4 v = *(const float4*)(emis + s * NN + g * 4);
      ssum[si] += __expf(v.x) + __expf(v.y) + __expf(v.z) + __expf(v.w);
    }
  }
  #pragma unroll
  for (int si = 0; si < 4; ++si) {
    float v = ssum[si];
    #pragma unroll
    for (int off = 32; off > 0; off >>= 1) v += __shfl_down(v, off);
    if (lane == 0) Z[wv * 4 + si] = v;
  }
  __syncthreads();                         // B1: trans staged, Z, p0 ready

  // ---- B: transition softmax -> Tp, Bb[0] = T ----
  {
    float m = -1e30f;
    #pragma unroll
    for (int k = 0; k < 16; ++k) m = fmaxf(m, Rb[0][i][k]);
    float sm = 0.f;
    #pragma unroll
    for (int k = 0; k < 16; ++k) sm += __expf(Rb[0][i][k] - m);
    const float tp = __expf(Rb[0][i][j] - m) / sm;
    __syncthreads();                       // B2: all raw reads done
    Tp[i][j] = tp;
    Bb[0][i][j] = tp;
  }
  __syncthreads();                         // B3

  // two squarings: Bb -> T^2 -> T^4 (ping-pong, 1 barrier each)
  int bs = 0;
  #pragma unroll
  for (int q = 0; q < 2; ++q) {
    float acc = 0.f;
    #pragma unroll
    for (int k = 0; k < 16; ++k) acc += Bb[bs][i][k] * Bb[bs][k][j];
    Bb[bs ^ 1][i][j] = acc;
    __syncthreads();
    bs ^= 1;
  }

  // binary powering: R = (T^4)^by  (<=8 iterations, 1 barrier each)
  int e = blockIdx.y;                      // block-uniform
  int rs = 0;
  bool rvalid = false;
  while (e) {
    const bool mul = (e & 1);
    float accR = 0.f, accB = 0.f;
    if (mul) {
      if (rvalid) {
        #pragma unroll
        for (int k = 0; k < 16; ++k) accR += Rb[rs][i][k] * Bb[bs][k][j];
      } else {
        accR = Bb[bs][i][j];
      }
    }
    #pragma unroll
    for (int k = 0; k < 16; ++k) accB += Bb[bs][i][k] * Bb[bs][k][j];
    // writes go to opposite buffers -> no pre-write barrier needed
    if (mul) Rb[rs ^ 1][i][j] = accR;
    Bb[bs ^ 1][i][j] = accB;
    __syncthreads();
    if (mul) { rs ^= 1; rvalid = true; }
    bs ^= 1;
    e >>= 1;
  }

  // w[0] = p0 @ R (or p0 if by==0); w[tt] = w[tt-1] @ T
  if (tid < 16) {
    if (rvalid) {
      float acc = 0.f;
      #pragma unroll
      for (int k = 0; k < 16; ++k) acc += p0v[k] * Rb[rs][k][tid];
      wrow[0][tid] = acc;
    } else {
      wrow[0][tid] = p0v[tid];
    }
  }
  __syncthreads();
  for (int tt = 1; tt < 4; ++tt) {
    if (tid < 16) {
      float acc = 0.f;
      #pragma unroll
      for (int k = 0; k < 16; ++k) acc += wrow[tt - 1][k] * Tp[k][tid];
      wrow[tt][tid] = acc;
    }
    __syncthreads();
  }
  // wd in place: each of threads 0..63 touches only its own element
  if (tid < 64) wrow[tid >> 4][tid & 15] /= Z[tid & 15];
  __syncthreads();

  // ---- C: output for this block's n-half, 4 t rows ----
  const int g = blockIdx.x * 256 + tid;    // float4 group id
  if (g < 500) {
    float4 ex[16];
    #pragma unroll
    for (int s = 0; s < 16; ++s) {
      float4 v = *(const float4*)(emis + s * NN + g * 4);
      ex[s].x = __expf(v.x); ex[s].y = __expf(v.y);
      ex[s].z = __expf(v.z); ex[s].w = __expf(v.w);
    }
    const int tbase = blockIdx.y * 4;
    #pragma unroll
    for (int tt = 0; tt < 4; ++tt) {
      float4 acc = make_float4(0.f, 0.f, 0.f, 0.f);
      #pragma unroll
      for (int s = 0; s < 16; ++s) {
        const float p = wrow[tt][s];
        acc.x += p * ex[s].x; acc.y += p * ex[s].y;
        acc.z += p * ex[s].z; acc.w += p * ex[s].w;
      }
      float4 o;
      o.x = __logf(acc.x); o.y = __logf(acc.y);
      o.z = __logf(acc.z); o.w = __logf(acc.w);
      *(float4*)(out + (tbase + tt) * NN + g * 4) = o;
    }
  }
}

extern "C" void kernel_launch(void* const* d_in, const int* in_sizes, int n_in,
                              void* d_out, int out_size, void* d_ws, size_t ws_size,
                              hipStream_t stream) {
  const float* init  = (const float*)d_in[0];   // (16,)
  // d_in[1] chain weights: log_softmax rows -> logsumexp over chains == 0, cancels
  const float* emis  = (const float*)d_in[2];   // (16,2000)
  const float* trans = (const float*)d_in[3];   // (16,16)
  float* out = (float*)d_out;                   // (1000,2000) f32

  hipLaunchKernelGGL(ssm_fused, dim3(2, 250), dim3(256), 0, stream,
                     init, emis, trans, out);
}